// Round 17
// baseline (851.010 us; speedup 1.0000x reference)
//
#include <hip/hip_runtime.h>
#include <hip/hip_fp16.h>
#include <math.h>

static constexpr float NEG_SLOPE = 0.2f;
static constexpr int P      = 256;    // node ranges for bucket sort
static constexpr int CAP    = 14000;  // staging capacity per range (mean 12.5K, +13 sigma)
static constexpr int CHSZ   = 4096;   // phase-1 chunk (edges) — R14/R16 measured best

__device__ __forceinline__ float lrelu(float x) { return x > 0.0f ? x : NEG_SLOPE * x; }

// divide by runtime npr via magic multiply (+/-1 fixup)
__device__ __forceinline__ void dm(int x, unsigned int mg, int npr, int& r, int& lk) {
    r = (int)__umulhi((unsigned int)x, mg);
    lk = x - r * npr;
    if (lk >= npr) { lk -= npr; ++r; }
    else if (lk < 0) { lk += npr; --r; }
}

union H8 { int4 i4; __half2 h2[4]; };

__device__ __forceinline__ void h8_to_f(int4 v, float* o) {
    H8 u; u.i4 = v;
#pragma unroll
    for (int k = 0; k < 4; ++k) {
        float2 f = __half22float2(u.h2[k]);
        o[2 * k] = f.x; o[2 * k + 1] = f.y;
    }
}

__device__ __forceinline__ int4 f_to_h8(const float* s) {
    H8 u;
#pragma unroll
    for (int k = 0; k < 4; ++k)
        u.h2[k] = __float22half2_rn(make_float2(s[2 * k], s[2 * k + 1]));
    return u.i4;
}

// ============ Build Phase 1: ONE (chunk, dir) per block (R14 config) ==========
__global__ __launch_bounds__(256) void part2_kernel(
    const int* __restrict__ src, const int* __restrict__ dst,
    int* __restrict__ gcount,
    unsigned int* __restrict__ stgd, unsigned int* __restrict__ stgs,
    int E, int npr, unsigned int mg)
{
    __shared__ int cntw[4 * P];          // per-wave counts, then per-wave tickets
    __shared__ int base[P];
    __shared__ int pref[P];
    __shared__ int wsum[4];
    __shared__ unsigned int buf[CHSZ];
    __shared__ unsigned char rid[CHSZ];
    const int dir = blockIdx.x & 1;
    const int c = blockIdx.x >> 1;
    const int i0 = c * CHSZ;
    const int i1 = min(i0 + CHSZ, E);
    const int tot = i1 - i0;
    const int tid = threadIdx.x;
    const int lane = tid & 63, w = tid >> 6;
    const int* key = dir ? (src + i0) : (dst + i0);
    const int* val = dir ? (dst + i0) : (src + i0);
    unsigned int* stg = dir ? stgs : stgd;
    int* gc = gcount + dir * P;
    int* mycnt = cntw + w * P;
#pragma unroll
    for (int q = 0; q < 4; ++q) cntw[q * P + tid] = 0;
    __syncthreads();
    const int nv = tot >> 2;
    const int4* k4 = (const int4*)key;
    for (int t = tid; t < nv; t += 256) {
        int4 k = k4[t];
        int r, lk;
        dm(k.x, mg, npr, r, lk); atomicAdd(&mycnt[r], 1);
        dm(k.y, mg, npr, r, lk); atomicAdd(&mycnt[r], 1);
        dm(k.z, mg, npr, r, lk); atomicAdd(&mycnt[r], 1);
        dm(k.w, mg, npr, r, lk); atomicAdd(&mycnt[r], 1);
    }
    for (int i = (nv << 2) + tid; i < tot; i += 256) {
        int r, lk;
        dm(key[i], mg, npr, r, lk);
        atomicAdd(&mycnt[r], 1);
    }
    __syncthreads();
    int c0 = cntw[0 * P + tid], c1 = cntw[1 * P + tid];
    int c2 = cntw[2 * P + tid], c3 = cntw[3 * P + tid];
    int tb = c0 + c1 + c2 + c3;
    base[tid] = atomicAdd(&gc[tid], tb);
    int x = tb;
#pragma unroll
    for (int off = 1; off < 64; off <<= 1) {
        int y = __shfl_up(x, off);
        if (lane >= off) x += y;
    }
    if (lane == 63) wsum[w] = x;
    __syncthreads();
    int wpref = 0;
#pragma unroll
    for (int k = 0; k < 4; ++k) if (k < w) wpref += wsum[k];
    int ex = x + wpref - tb;
    pref[tid] = ex;
    cntw[0 * P + tid] = ex;
    cntw[1 * P + tid] = ex + c0;
    cntw[2 * P + tid] = ex + c0 + c1;
    cntw[3 * P + tid] = ex + c0 + c1 + c2;
    __syncthreads();
    int* mytick = cntw + w * P;
    for (int t = tid; t < nv; t += 256) {
        int4 k = k4[t];
        const int4* v4 = (const int4*)val;
        int4 v = v4[t];
        int r, lk, p;
        dm(k.x, mg, npr, r, lk); p = atomicAdd(&mytick[r], 1);
        buf[p] = ((unsigned int)lk << 17) | (unsigned int)v.x; rid[p] = (unsigned char)r;
        dm(k.y, mg, npr, r, lk); p = atomicAdd(&mytick[r], 1);
        buf[p] = ((unsigned int)lk << 17) | (unsigned int)v.y; rid[p] = (unsigned char)r;
        dm(k.z, mg, npr, r, lk); p = atomicAdd(&mytick[r], 1);
        buf[p] = ((unsigned int)lk << 17) | (unsigned int)v.z; rid[p] = (unsigned char)r;
        dm(k.w, mg, npr, r, lk); p = atomicAdd(&mytick[r], 1);
        buf[p] = ((unsigned int)lk << 17) | (unsigned int)v.w; rid[p] = (unsigned char)r;
    }
    for (int i = (nv << 2) + tid; i < tot; i += 256) {
        int r, lk;
        dm(key[i], mg, npr, r, lk);
        int p = atomicAdd(&mytick[r], 1);
        buf[p] = ((unsigned int)lk << 17) | (unsigned int)val[i];
        rid[p] = (unsigned char)r;
    }
    __syncthreads();
    for (int i = tid; i < tot; i += 256) {
        int r = (int)rid[i];
        int b = base[r] + (i - pref[r]);
        if (b < CAP) stg[(size_t)r * CAP + b] = buf[i];
    }
}

// ============ Tiny scan: per-range edge bases (exclusive, per direction) ======
__global__ __launch_bounds__(512) void ebase_kernel(
    const int* __restrict__ gtot, int* __restrict__ ebase)
{
    __shared__ int sm[2 * P];
    int tid = threadIdx.x;
    int v = gtot[tid];
    sm[tid] = v;
    __syncthreads();
#pragma unroll
    for (int off = 1; off < P; off <<= 1) {
        int t = ((tid & (P - 1)) >= off) ? sm[tid - off] : 0;
        __syncthreads();
        sm[tid] += t;
        __syncthreads();
    }
    ebase[tid] = sm[tid] - v;
}

// ============ Build Phase 2: per-range counting sort via LDS, streamed out ====
__global__ __launch_bounds__(512) void build_kernel(
    const unsigned int* __restrict__ stgd, const unsigned int* __restrict__ stgs,
    const int* __restrict__ gtot, const int* __restrict__ ebase,
    int* __restrict__ col_dst, int* __restrict__ col_src,
    int* __restrict__ deg_dst, int* __restrict__ deg_src,
    int* __restrict__ row_dst, int* __restrict__ row_src,
    int N, int npr)
{
    __shared__ int cntw[2 * 512];
    __shared__ int scn[512];
    __shared__ int outv[CAP];
    const int dir = blockIdx.x >> 8;
    const int r = blockIdx.x & (P - 1);
    const unsigned int* stg = (dir ? stgs : stgd) + (size_t)r * CAP;
    int tot = gtot[dir * P + r];
    if (tot > CAP) tot = CAP;
    const int n0 = r * npr;
    const int nb = min(npr, N - n0);
    const int tid = threadIdx.x;
    const int g = tid >> 8;
    int* mycnt = cntw + g * 512;
    cntw[tid] = 0; cntw[512 + tid] = 0;
    __syncthreads();
    for (int i = tid; i < tot; i += 512)
        atomicAdd(&mycnt[stg[i] >> 17], 1);
    __syncthreads();
    int c0 = cntw[tid], c1 = cntw[512 + tid];
    int v = c0 + c1;
    scn[tid] = v;
    __syncthreads();
#pragma unroll
    for (int off = 1; off < 512; off <<= 1) {
        int t = (tid >= off) ? scn[tid - off] : 0;
        __syncthreads();
        scn[tid] += t;
        __syncthreads();
    }
    int ex = scn[tid] - v;
    const int eb = ebase[dir * P + r];
    if (tid < nb) {
        (dir ? deg_src : deg_dst)[n0 + tid] = v;
        (dir ? row_src : row_dst)[n0 + tid] = eb + ex;
    }
    cntw[tid] = ex;
    cntw[512 + tid] = ex + c0;
    __syncthreads();
    for (int i = tid; i < tot; i += 512) {
        unsigned int w = stg[i];
        int t = atomicAdd(&mycnt[w >> 17], 1);
        outv[t] = (int)(w & 0x1FFFFu);
    }
    __syncthreads();
    int* col = (dir ? col_src : col_dst) + eb;
    for (int i = tid; i < tot; i += 512) col[i] = outv[i];
}

// ============ Layer 1: h0 = relu(x1 @ lin1_w^T + b) ===========================
__global__ __launch_bounds__(256) void l1h0_kernel(
    const float* __restrict__ x1, const float* __restrict__ lin1_w,
    const float* __restrict__ lin1_b, float* __restrict__ h0, int N)
{
    int n = blockIdx.x * blockDim.x + threadIdx.x;
    if (n >= N) return;
    float acc = lin1_b[0];
#pragma unroll
    for (int k = 0; k < 7; ++k) acc = fmaf(x1[n * 7 + k], lin1_w[k], acc);
    h0[n] = fmaxf(acc, 0.0f);
}

// ============ Layer-1 gather (rank-1) FUSED with node2: writes h2 fp16 ========
// Each lane computes its head's 4 x3 values in-register, then partial
// h2[16] over its 4 rows of W2; 3-stage butterfly sums; lanes 0-1 write
// the 32 B fp16 row. x3 never touches memory.
__global__ __launch_bounds__(256) void gat_gather1_kernel(
    const int* __restrict__ row_start, const int* __restrict__ degv,
    const int* __restrict__ col, const float* __restrict__ h0,
    const float* __restrict__ W1, const float* __restrict__ a_src,
    const float* __restrict__ a_dst, const float* __restrict__ bias,
    const float* __restrict__ W2, int4* __restrict__ h2p, int N)
{
    int t = blockIdx.x * 256 + threadIdx.x;
    int n = t >> 3, lane = t & 7;
    if (n >= N) return;
    float cs[8], cd[8];
#pragma unroll
    for (int hd = 0; hd < 8; ++hd) {
        float s = 0.0f, d = 0.0f;
#pragma unroll
        for (int c = 0; c < 4; ++c) {
            s = fmaf(W1[hd * 4 + c], a_src[hd * 4 + c], s);
            d = fmaf(W1[hd * 4 + c], a_dst[hd * 4 + c], d);
        }
        cs[hd] = s; cd[hd] = d;
    }
    float h0n = h0[n];
    float wh[8], den[8], adn[8];
#pragma unroll
    for (int hd = 0; hd < 8; ++hd) {
        adn[hd] = h0n * cd[hd];
        if (lane == 0) {
            float w = __expf(lrelu(h0n * cs[hd] + adn[hd]));
            den[hd] = w; wh[hd] = w * h0n;
        } else { den[hd] = 0.0f; wh[hd] = 0.0f; }
    }
    int start = row_start[n];
    int end = start + degv[n];
    for (int e = start + lane; e < end; e += 8) {
        int s = col[e];
        if (s == n) continue;
        float hs = h0[s];
#pragma unroll
        for (int hd = 0; hd < 8; ++hd) {
            float w = __expf(lrelu(hs * cs[hd] + adn[hd]));
            den[hd] += w;
            wh[hd] = fmaf(w, hs, wh[hd]);
        }
    }
#pragma unroll
    for (int m = 1; m < 8; m <<= 1) {
#pragma unroll
        for (int hd = 0; hd < 8; ++hd) {
            den[hd] += __shfl_xor(den[hd], m);
            wh[hd]  += __shfl_xor(wh[hd], m);
        }
    }
    // own head's x3 values (k-rows lane*4 .. lane*4+3)
    float fct = wh[lane] / den[lane];
    const float4 wv = ((const float4*)W1)[lane];
    const float4 bb = ((const float4*)bias)[lane];
    float x3v[4];
    x3v[0] = fmaxf(fmaf(fct, wv.x, bb.x), 0.0f);
    x3v[1] = fmaxf(fmaf(fct, wv.y, bb.y), 0.0f);
    x3v[2] = fmaxf(fmaf(fct, wv.z, bb.z), 0.0f);
    x3v[3] = fmaxf(fmaf(fct, wv.w, bb.w), 0.0f);
    // fused node2: partial h2 = x3(own rows) @ W2, butterfly-summed
    float ph[16];
#pragma unroll
    for (int j = 0; j < 16; ++j) ph[j] = 0.0f;
#pragma unroll
    for (int c = 0; c < 4; ++c) {
        const float* w2r = W2 + (size_t)(lane * 4 + c) * 16;
#pragma unroll
        for (int j = 0; j < 16; ++j) ph[j] = fmaf(x3v[c], w2r[j], ph[j]);
    }
#pragma unroll
    for (int m = 1; m < 8; m <<= 1) {
#pragma unroll
        for (int j = 0; j < 16; ++j) ph[j] += __shfl_xor(ph[j], m);
    }
    if (lane < 2) h2p[(size_t)n * 2 + lane] = f_to_h8(ph + lane * 8);
}

// ============ Layer-2 gather FUSED with node3: writes h3 fp16 =================
__global__ __launch_bounds__(256) void gat_gather2_kernel(
    const int* __restrict__ row_start, const int* __restrict__ degv,
    const int* __restrict__ col, const int4* __restrict__ hp,
    const float* __restrict__ a_src, const float* __restrict__ a_dst,
    const float* __restrict__ bias, const float* __restrict__ W3,
    int4* __restrict__ h3p, int N)
{
    int t = blockIdx.x * 256 + threadIdx.x;
    int n = t >> 3, lane = t & 7;
    if (n >= N) return;
    float As[16], Ad[16];
#pragma unroll
    for (int j = 0; j < 16; ++j) { As[j] = a_src[j]; Ad[j] = a_dst[j]; }
    float hn[16];
    h8_to_f(hp[(size_t)n * 2], hn);
    h8_to_f(hp[(size_t)n * 2 + 1], hn + 8);
    float ald[4];
#pragma unroll
    for (int hd = 0; hd < 4; ++hd) {
        float d = 0.0f;
#pragma unroll
        for (int c = 0; c < 4; ++c) d = fmaf(hn[hd * 4 + c], Ad[hd * 4 + c], d);
        ald[hd] = d;
    }
    float num[16], den[4];
    if (lane == 0) {
#pragma unroll
        for (int hd = 0; hd < 4; ++hd) {
            float a = 0.0f;
#pragma unroll
            for (int c = 0; c < 4; ++c) a = fmaf(hn[hd * 4 + c], As[hd * 4 + c], a);
            float w = __expf(lrelu(a + ald[hd]));
            den[hd] = w;
#pragma unroll
            for (int c = 0; c < 4; ++c) num[hd * 4 + c] = w * hn[hd * 4 + c];
        }
    } else {
#pragma unroll
        for (int j = 0; j < 16; ++j) num[j] = 0.0f;
#pragma unroll
        for (int hd = 0; hd < 4; ++hd) den[hd] = 0.0f;
    }
    int start = row_start[n];
    int end = start + degv[n];
    for (int e = start + lane; e < end; e += 8) {
        int s = col[e];
        if (s == n) continue;
        float hs[16];
        h8_to_f(hp[(size_t)s * 2], hs);
        h8_to_f(hp[(size_t)s * 2 + 1], hs + 8);
#pragma unroll
        for (int hd = 0; hd < 4; ++hd) {
            float a = 0.0f;
#pragma unroll
            for (int c = 0; c < 4; ++c) a = fmaf(hs[hd * 4 + c], As[hd * 4 + c], a);
            float w = __expf(lrelu(a + ald[hd]));
            den[hd] += w;
#pragma unroll
            for (int c = 0; c < 4; ++c) num[hd * 4 + c] = fmaf(w, hs[hd * 4 + c], num[hd * 4 + c]);
        }
    }
#pragma unroll
    for (int m = 1; m < 8; m <<= 1) {
#pragma unroll
        for (int hd = 0; hd < 4; ++hd) den[hd] += __shfl_xor(den[hd], m);
#pragma unroll
        for (int j = 0; j < 16; ++j) num[j] += __shfl_xor(num[j], m);
    }
    // fused node3: x4 (own head, lanes 0-3) @ W3, butterfly-summed
    float ph[8];
#pragma unroll
    for (int j = 0; j < 8; ++j) ph[j] = 0.0f;
    if (lane < 4) {
        float inv = 1.0f / den[lane];
        const float4 bb = ((const float4*)bias)[lane];
        float x4v[4];
        x4v[0] = fmaxf(fmaf(num[lane * 4 + 0], inv, bb.x), 0.0f);
        x4v[1] = fmaxf(fmaf(num[lane * 4 + 1], inv, bb.y), 0.0f);
        x4v[2] = fmaxf(fmaf(num[lane * 4 + 2], inv, bb.z), 0.0f);
        x4v[3] = fmaxf(fmaf(num[lane * 4 + 3], inv, bb.w), 0.0f);
#pragma unroll
        for (int c = 0; c < 4; ++c) {
            const float* w3r = W3 + (size_t)(lane * 4 + c) * 8;
#pragma unroll
            for (int j = 0; j < 8; ++j) ph[j] = fmaf(x4v[c], w3r[j], ph[j]);
        }
    }
#pragma unroll
    for (int m = 1; m < 8; m <<= 1) {
#pragma unroll
        for (int j = 0; j < 8; ++j) ph[j] += __shfl_xor(ph[j], m);
    }
    if (lane == 0) h3p[n] = f_to_h8(ph);
}

// ============ Layer-3 gather: H=2, fp16 rows (16 B), W=4, fp16 x6 out =========
__global__ __launch_bounds__(256) void gat_gather3_kernel(
    const int* __restrict__ row_start, const int* __restrict__ degv,
    const int* __restrict__ col, const int4* __restrict__ hp,
    const float* __restrict__ a_src, const float* __restrict__ a_dst,
    const float* __restrict__ bias, int4* __restrict__ x6p, int N)
{
    int t = blockIdx.x * 256 + threadIdx.x;
    int n = t >> 2, lane = t & 3;
    if (n >= N) return;
    float As[8], Ad[8];
#pragma unroll
    for (int j = 0; j < 8; ++j) { As[j] = a_src[j]; Ad[j] = a_dst[j]; }
    float hn[8];
    h8_to_f(hp[n], hn);
    float ald[2];
#pragma unroll
    for (int hd = 0; hd < 2; ++hd) {
        float d = 0.0f;
#pragma unroll
        for (int c = 0; c < 4; ++c) d = fmaf(hn[hd * 4 + c], Ad[hd * 4 + c], d);
        ald[hd] = d;
    }
    float num[8], den[2];
    if (lane == 0) {
#pragma unroll
        for (int hd = 0; hd < 2; ++hd) {
            float a = 0.0f;
#pragma unroll
            for (int c = 0; c < 4; ++c) a = fmaf(hn[hd * 4 + c], As[hd * 4 + c], a);
            float w = __expf(lrelu(a + ald[hd]));
            den[hd] = w;
#pragma unroll
            for (int c = 0; c < 4; ++c) num[hd * 4 + c] = w * hn[hd * 4 + c];
        }
    } else {
#pragma unroll
        for (int j = 0; j < 8; ++j) num[j] = 0.0f;
        den[0] = den[1] = 0.0f;
    }
    int start = row_start[n];
    int end = start + degv[n];
    for (int e = start + lane; e < end; e += 4) {
        int s = col[e];
        if (s == n) continue;
        float hs[8];
        h8_to_f(hp[s], hs);
#pragma unroll
        for (int hd = 0; hd < 2; ++hd) {
            float a = 0.0f;
#pragma unroll
            for (int c = 0; c < 4; ++c) a = fmaf(hs[hd * 4 + c], As[hd * 4 + c], a);
            float w = __expf(lrelu(a + ald[hd]));
            den[hd] += w;
#pragma unroll
            for (int c = 0; c < 4; ++c) num[hd * 4 + c] = fmaf(w, hs[hd * 4 + c], num[hd * 4 + c]);
        }
    }
#pragma unroll
    for (int m = 1; m < 4; m <<= 1) {
        den[0] += __shfl_xor(den[0], m);
        den[1] += __shfl_xor(den[1], m);
#pragma unroll
        for (int j = 0; j < 8; ++j) num[j] += __shfl_xor(num[j], m);
    }
    if (lane == 0) {
        float o[8];
        float i0 = 1.0f / den[0], i1 = 1.0f / den[1];
#pragma unroll
        for (int c = 0; c < 4; ++c) {
            o[c]     = fmaxf(fmaf(num[c], i0, bias[c]), 0.0f);
            o[4 + c] = fmaxf(fmaf(num[4 + c], i1, bias[4 + c]), 0.0f);
        }
        x6p[n] = f_to_h8(o);
    }
}

// ============ Final scoring: by-src CSR, fp16 x6, W=4 =========================
// Algebra: local = x6[n] . R3raw[n], so the edge loop only sums neighbors.
__global__ __launch_bounds__(256) void score_gather_kernel(
    const int* __restrict__ row_start, const int* __restrict__ degv,
    const int* __restrict__ col, const int4* __restrict__ x6p,
    const float* __restrict__ lin2_w, float* __restrict__ out, int N)
{
    int t = blockIdx.x * 256 + threadIdx.x;
    int n = t >> 2, lane = t & 3;
    if (n >= N) return;
    float sx[8];
    h8_to_f(x6p[n], sx);
    float r[8];
    int sc = 0;
    if (lane == 0) {
#pragma unroll
        for (int j = 0; j < 8; ++j) r[j] = sx[j];   // self term of R3raw
    } else {
#pragma unroll
        for (int j = 0; j < 8; ++j) r[j] = 0.0f;
    }
    int start = row_start[n];
    int dg = degv[n];
    int end = start + dg;
    for (int e = start + lane; e < end; e += 4) {
        int d = col[e];
        if (d == n) { ++sc; continue; }
        float dx[8];
        h8_to_f(x6p[d], dx);
#pragma unroll
        for (int j = 0; j < 8; ++j) r[j] += dx[j];
    }
#pragma unroll
    for (int m = 1; m < 4; m <<= 1) {
        sc += __shfl_xor(sc, m);
#pragma unroll
        for (int j = 0; j < 8; ++j) r[j] += __shfl_xor(r[j], m);
    }
    if (lane == 0) {
        float invd = 1.0f / (1.0f + (float)(dg - sc));
        float loc = 0.0f, g = 0.0f;
#pragma unroll
        for (int j = 0; j < 8; ++j) {
            loc = fmaf(sx[j], r[j], loc);
            g   = fmaf(r[j], lin2_w[j], g);
        }
        out[n] = (loc + g) * invd;
    }
}

extern "C" void kernel_launch(void* const* d_in, const int* in_sizes, int n_in,
                              void* d_out, int out_size, void* d_ws, size_t ws_size,
                              hipStream_t stream)
{
    const float* x1     = (const float*)d_in[0];
    const int*   ei     = (const int*)d_in[2];
    const float* lin1_w = (const float*)d_in[4];
    const float* lin1_b = (const float*)d_in[5];
    const float* lin2_w = (const float*)d_in[6];
    const float* W1     = (const float*)d_in[7];
    const float* a_src1 = (const float*)d_in[8];
    const float* a_dst1 = (const float*)d_in[9];
    const float* b1     = (const float*)d_in[10];
    const float* W2     = (const float*)d_in[11];
    const float* a_src2 = (const float*)d_in[12];
    const float* a_dst2 = (const float*)d_in[13];
    const float* b2     = (const float*)d_in[14];
    const float* W3     = (const float*)d_in[15];
    const float* a_src3 = (const float*)d_in[16];
    const float* a_dst3 = (const float*)d_in[17];
    const float* b3     = (const float*)d_in[18];
    float* out = (float*)d_out;

    const int N = in_sizes[0] / 7;   // 100000
    const int E = in_sizes[2] / 2;   // 3200000
    const int* src = ei;
    const int* dst = ei + E;

    const int npr = (N + P - 1) / P; // 391 nodes per range (<= 512 for build TB)
    const unsigned int mg = (unsigned int)((0x100000000ULL + npr - 1) / (unsigned long long)npr);
    const int PB = (E + CHSZ - 1) / CHSZ;  // 782 chunks

    // ---- workspace layout ----
    size_t Ns = (size_t)N, Es = (size_t)E;
    int* ideg_dst = (int*)d_ws;
    int* ideg_src = ideg_dst + Ns;
    int* irow_dst = ideg_src + Ns;
    int* irow_src = irow_dst + Ns;
    int* gcount   = irow_src + Ns;        // 2P ints (totals after part2)
    int* iebase   = gcount + 2 * P;       // 2P ints
    int* icol_dst = iebase + 2 * P;
    int* icol_src = icol_dst + Es;
    float* f = (float*)(icol_src + Es);   // 80N float region
    // staging (2*P*CAP = 7.17M words = 71.7N) aliases f; dies after build_kernel
    unsigned int* stgd = (unsigned int*)f;
    unsigned int* stgs = stgd + (size_t)P * CAP;
    // fp16/float buffers, born after build (disjoint; h2p/h3p/x6p/h0 fit easily):
    float* h0  = f;                        // [0, N)
    int4*  h2p = (int4*)(f + 33 * Ns);     // [33N, 41N)    fp16 [N,16] (32 B rows)
    int4*  h3p = (int4*)(f + 57 * Ns);     // [57N, 61N)    fp16 [N,8]  (16 B rows)
    int4*  x6p = (int4*)(f + 61 * Ns);     // [61N, 65N)    fp16 [N,8]

    const int TB = 256;
    const int gN = (N + TB - 1) / TB;
    const int g8 = (8 * N + TB - 1) / TB;
    const int g4 = (4 * N + TB - 1) / TB;

    // ---- CSR build: single-pass partition (per-dir blocks) + per-range sort ----
    hipMemsetAsync(gcount, 0, 2 * P * sizeof(int), stream);
    part2_kernel<<<2 * PB, 256, 0, stream>>>(src, dst, gcount, stgd, stgs, E, npr, mg);
    ebase_kernel<<<1, 2 * P, 0, stream>>>(gcount, iebase);
    build_kernel<<<2 * P, 512, 0, stream>>>(stgd, stgs, gcount, iebase,
                                            icol_dst, icol_src,
                                            ideg_dst, ideg_src,
                                            irow_dst, irow_src, N, npr);

    // ---- Layer 1 (rank-1) fused with node2 ----
    l1h0_kernel<<<gN, TB, 0, stream>>>(x1, lin1_w, lin1_b, h0, N);
    gat_gather1_kernel<<<g8, TB, 0, stream>>>(irow_dst, ideg_dst, icol_dst,
                                              h0, W1, a_src1, a_dst1, b1,
                                              W2, h2p, N);

    // ---- Layer 2 fused with node3 ----
    gat_gather2_kernel<<<g8, TB, 0, stream>>>(irow_dst, ideg_dst, icol_dst,
                                              h2p, a_src2, a_dst2, b2,
                                              W3, h3p, N);

    // ---- Layer 3 ----
    gat_gather3_kernel<<<g4, TB, 0, stream>>>(irow_dst, ideg_dst, icol_dst,
                                              h3p, a_src3, a_dst3, b3, x6p, N);

    // ---- Final scoring (by-src CSR) ----
    score_gather_kernel<<<g4, TB, 0, stream>>>(irow_src, ideg_src, icol_src,
                                               x6p, lin2_w, out, N);
}

// Round 18
// 270.874 us; speedup vs baseline: 3.1417x; 3.1417x over previous
//
#include <hip/hip_runtime.h>
#include <hip/hip_fp16.h>
#include <math.h>

static constexpr float NEG_SLOPE = 0.2f;
static constexpr int P      = 256;    // node ranges for bucket sort
static constexpr int CAP    = 14000;  // staging capacity per range (mean 12.5K, +13 sigma)
static constexpr int CHSZ   = 4096;   // phase-1 chunk (edges) — R14/R16 measured best

__device__ __forceinline__ float lrelu(float x) { return x > 0.0f ? x : NEG_SLOPE * x; }

// divide by runtime npr via magic multiply (+/-1 fixup)
__device__ __forceinline__ void dm(int x, unsigned int mg, int npr, int& r, int& lk) {
    r = (int)__umulhi((unsigned int)x, mg);
    lk = x - r * npr;
    if (lk >= npr) { lk -= npr; ++r; }
    else if (lk < 0) { lk += npr; --r; }
}

union H8 { int4 i4; __half2 h2[4]; };

__device__ __forceinline__ void h8_to_f(int4 v, float* o) {
    H8 u; u.i4 = v;
#pragma unroll
    for (int k = 0; k < 4; ++k) {
        float2 f = __half22float2(u.h2[k]);
        o[2 * k] = f.x; o[2 * k + 1] = f.y;
    }
}

__device__ __forceinline__ int4 f_to_h8(const float* s) {
    H8 u;
#pragma unroll
    for (int k = 0; k < 4; ++k)
        u.h2[k] = __float22half2_rn(make_float2(s[2 * k], s[2 * k + 1]));
    return u.i4;
}

// ============ Build Phase 1: ONE (chunk, dir) per block (R14 config) ==========
// Per-wave privatized count/ticket arrays, shfl-based bin scan, uint8 rid,
// CHSZ=4096 (per-block overhead amortization beats occupancy — R15 lesson).
// Emit streams block-private contiguous runs (the only amplification-safe
// write pattern — R9/R11/R12-proven).
__global__ __launch_bounds__(256) void part2_kernel(
    const int* __restrict__ src, const int* __restrict__ dst,
    int* __restrict__ gcount,
    unsigned int* __restrict__ stgd, unsigned int* __restrict__ stgs,
    int E, int npr, unsigned int mg)
{
    __shared__ int cntw[4 * P];          // per-wave counts, then per-wave tickets
    __shared__ int base[P];
    __shared__ int pref[P];
    __shared__ int wsum[4];
    __shared__ unsigned int buf[CHSZ];
    __shared__ unsigned char rid[CHSZ];
    const int dir = blockIdx.x & 1;
    const int c = blockIdx.x >> 1;
    const int i0 = c * CHSZ;
    const int i1 = min(i0 + CHSZ, E);
    const int tot = i1 - i0;
    const int tid = threadIdx.x;
    const int lane = tid & 63, w = tid >> 6;
    const int* key = dir ? (src + i0) : (dst + i0);
    const int* val = dir ? (dst + i0) : (src + i0);
    unsigned int* stg = dir ? stgs : stgd;
    int* gc = gcount + dir * P;
    int* mycnt = cntw + w * P;
#pragma unroll
    for (int q = 0; q < 4; ++q) cntw[q * P + tid] = 0;
    __syncthreads();
    const int nv = tot >> 2;
    const int4* k4 = (const int4*)key;
    // ---- count (per-wave arrays; striding identical to sort loop) ----
    for (int t = tid; t < nv; t += 256) {
        int4 k = k4[t];
        int r, lk;
        dm(k.x, mg, npr, r, lk); atomicAdd(&mycnt[r], 1);
        dm(k.y, mg, npr, r, lk); atomicAdd(&mycnt[r], 1);
        dm(k.z, mg, npr, r, lk); atomicAdd(&mycnt[r], 1);
        dm(k.w, mg, npr, r, lk); atomicAdd(&mycnt[r], 1);
    }
    for (int i = (nv << 2) + tid; i < tot; i += 256) {
        int r, lk;
        dm(key[i], mg, npr, r, lk);
        atomicAdd(&mycnt[r], 1);
    }
    __syncthreads();
    // ---- combine + reserve + scan ----
    int c0 = cntw[0 * P + tid], c1 = cntw[1 * P + tid];
    int c2 = cntw[2 * P + tid], c3 = cntw[3 * P + tid];
    int tb = c0 + c1 + c2 + c3;
    base[tid] = atomicAdd(&gc[tid], tb);
    // shfl inclusive scan within wave over bins
    int x = tb;
#pragma unroll
    for (int off = 1; off < 64; off <<= 1) {
        int y = __shfl_up(x, off);
        if (lane >= off) x += y;
    }
    if (lane == 63) wsum[w] = x;
    __syncthreads();
    int wpref = 0;
#pragma unroll
    for (int k = 0; k < 4; ++k) if (k < w) wpref += wsum[k];
    int ex = x + wpref - tb;   // exclusive prefix of bin tid
    pref[tid] = ex;
    // per-wave ticket bases (wave-major order within each bin's run)
    cntw[0 * P + tid] = ex;
    cntw[1 * P + tid] = ex + c0;
    cntw[2 * P + tid] = ex + c0 + c1;
    cntw[3 * P + tid] = ex + c0 + c1 + c2;
    __syncthreads();
    // ---- sort (per-wave tickets; same striding as count) ----
    int* mytick = cntw + w * P;
    for (int t = tid; t < nv; t += 256) {
        int4 k = k4[t];
        const int4* v4 = (const int4*)val;
        int4 v = v4[t];
        int r, lk, p;
        dm(k.x, mg, npr, r, lk); p = atomicAdd(&mytick[r], 1);
        buf[p] = ((unsigned int)lk << 17) | (unsigned int)v.x; rid[p] = (unsigned char)r;
        dm(k.y, mg, npr, r, lk); p = atomicAdd(&mytick[r], 1);
        buf[p] = ((unsigned int)lk << 17) | (unsigned int)v.y; rid[p] = (unsigned char)r;
        dm(k.z, mg, npr, r, lk); p = atomicAdd(&mytick[r], 1);
        buf[p] = ((unsigned int)lk << 17) | (unsigned int)v.z; rid[p] = (unsigned char)r;
        dm(k.w, mg, npr, r, lk); p = atomicAdd(&mytick[r], 1);
        buf[p] = ((unsigned int)lk << 17) | (unsigned int)v.w; rid[p] = (unsigned char)r;
    }
    for (int i = (nv << 2) + tid; i < tot; i += 256) {
        int r, lk;
        dm(key[i], mg, npr, r, lk);
        int p = atomicAdd(&mytick[r], 1);
        buf[p] = ((unsigned int)lk << 17) | (unsigned int)val[i];
        rid[p] = (unsigned char)r;
    }
    __syncthreads();
    // ---- emit contiguous runs; address recomputed from rid ----
    for (int i = tid; i < tot; i += 256) {
        int r = (int)rid[i];
        int b = base[r] + (i - pref[r]);
        if (b < CAP) stg[(size_t)r * CAP + b] = buf[i];
    }
}

// ============ Tiny scan: per-range edge bases (exclusive, per direction) ======
__global__ __launch_bounds__(512) void ebase_kernel(
    const int* __restrict__ gtot, int* __restrict__ ebase)
{
    __shared__ int sm[2 * P];
    int tid = threadIdx.x;
    int v = gtot[tid];
    sm[tid] = v;
    __syncthreads();
#pragma unroll
    for (int off = 1; off < P; off <<= 1) {
        int t = ((tid & (P - 1)) >= off) ? sm[tid - off] : 0;
        __syncthreads();
        sm[tid] += t;
        __syncthreads();
    }
    ebase[tid] = sm[tid] - v;  // exclusive within each direction half
}

// ============ Build Phase 2: per-range counting sort via LDS, streamed out ====
// Count/sort atomics split across 2 privatized copies (threads <256 vs >=256,
// identical striding in both loops) — halves LDS atomic contention.
__global__ __launch_bounds__(512) void build_kernel(
    const unsigned int* __restrict__ stgd, const unsigned int* __restrict__ stgs,
    const int* __restrict__ gtot, const int* __restrict__ ebase,
    int* __restrict__ col_dst, int* __restrict__ col_src,
    int* __restrict__ deg_dst, int* __restrict__ deg_src,
    int* __restrict__ row_dst, int* __restrict__ row_src,
    int N, int npr)
{
    __shared__ int cntw[2 * 512];
    __shared__ int scn[512];
    __shared__ int outv[CAP];
    const int dir = blockIdx.x >> 8;
    const int r = blockIdx.x & (P - 1);
    const unsigned int* stg = (dir ? stgs : stgd) + (size_t)r * CAP;
    int tot = gtot[dir * P + r];
    if (tot > CAP) tot = CAP;
    const int n0 = r * npr;
    const int nb = min(npr, N - n0);
    const int tid = threadIdx.x;
    const int g = tid >> 8;               // group 0: tid<256, group 1: tid>=256
    int* mycnt = cntw + g * 512;
    cntw[tid] = 0; cntw[512 + tid] = 0;
    __syncthreads();
    for (int i = tid; i < tot; i += 512)
        atomicAdd(&mycnt[stg[i] >> 17], 1);
    __syncthreads();
    int c0 = cntw[tid], c1 = cntw[512 + tid];
    int v = c0 + c1;
    scn[tid] = v;
    __syncthreads();
#pragma unroll
    for (int off = 1; off < 512; off <<= 1) {
        int t = (tid >= off) ? scn[tid - off] : 0;
        __syncthreads();
        scn[tid] += t;
        __syncthreads();
    }
    int ex = scn[tid] - v;
    const int eb = ebase[dir * P + r];
    if (tid < nb) {
        (dir ? deg_src : deg_dst)[n0 + tid] = v;
        (dir ? row_src : row_dst)[n0 + tid] = eb + ex;
    }
    cntw[tid] = ex;          // group-0 ticket base
    cntw[512 + tid] = ex + c0;  // group-1 ticket base
    __syncthreads();
    for (int i = tid; i < tot; i += 512) {
        unsigned int w = stg[i];
        int t = atomicAdd(&mycnt[w >> 17], 1);
        outv[t] = (int)(w & 0x1FFFFu);
    }
    __syncthreads();
    int* col = (dir ? col_src : col_dst) + eb;
    for (int i = tid; i < tot; i += 512) col[i] = outv[i];
}

// ============ Layer 1: h0 = relu(x1 @ lin1_w^T + b) ===========================
__global__ __launch_bounds__(256) void l1h0_kernel(
    const float* __restrict__ x1, const float* __restrict__ lin1_w,
    const float* __restrict__ lin1_b, float* __restrict__ h0, int N)
{
    int n = blockIdx.x * blockDim.x + threadIdx.x;
    if (n >= N) return;
    float acc = lin1_b[0];
#pragma unroll
    for (int k = 0; k < 7; ++k) acc = fmaf(x1[n * 7 + k], lin1_w[k], acc);
    h0[n] = fmaxf(acc, 0.0f);
}

// ============ Layer-1 gather (rank-1), 8 lanes per node =======================
__global__ __launch_bounds__(256) void gat_gather1_kernel(
    const int* __restrict__ row_start, const int* __restrict__ degv,
    const int* __restrict__ col, const float* __restrict__ h0,
    const float* __restrict__ W1, const float* __restrict__ a_src,
    const float* __restrict__ a_dst, const float* __restrict__ bias,
    float* __restrict__ x3, int N)
{
    int t = blockIdx.x * 256 + threadIdx.x;
    int n = t >> 3, lane = t & 7;
    if (n >= N) return;
    float cs[8], cd[8];
#pragma unroll
    for (int hd = 0; hd < 8; ++hd) {
        float s = 0.0f, d = 0.0f;
#pragma unroll
        for (int c = 0; c < 4; ++c) {
            s = fmaf(W1[hd * 4 + c], a_src[hd * 4 + c], s);
            d = fmaf(W1[hd * 4 + c], a_dst[hd * 4 + c], d);
        }
        cs[hd] = s; cd[hd] = d;
    }
    float h0n = h0[n];
    float wh[8], den[8], adn[8];
#pragma unroll
    for (int hd = 0; hd < 8; ++hd) {
        adn[hd] = h0n * cd[hd];
        if (lane == 0) {
            float w = __expf(lrelu(h0n * cs[hd] + adn[hd]));
            den[hd] = w; wh[hd] = w * h0n;
        } else { den[hd] = 0.0f; wh[hd] = 0.0f; }
    }
    int start = row_start[n];
    int end = start + degv[n];
    for (int e = start + lane; e < end; e += 8) {
        int s = col[e];
        if (s == n) continue;
        float hs = h0[s];
#pragma unroll
        for (int hd = 0; hd < 8; ++hd) {
            float w = __expf(lrelu(hs * cs[hd] + adn[hd]));
            den[hd] += w;
            wh[hd] = fmaf(w, hs, wh[hd]);
        }
    }
#pragma unroll
    for (int m = 1; m < 8; m <<= 1) {
#pragma unroll
        for (int hd = 0; hd < 8; ++hd) {
            den[hd] += __shfl_xor(den[hd], m);
            wh[hd]  += __shfl_xor(wh[hd], m);
        }
    }
    float fct = wh[lane] / den[lane];
    const float4 wv = ((const float4*)W1)[lane];
    const float4 bb = ((const float4*)bias)[lane];
    float4 r;
    r.x = fmaxf(fmaf(fct, wv.x, bb.x), 0.0f);
    r.y = fmaxf(fmaf(fct, wv.y, bb.y), 0.0f);
    r.z = fmaxf(fmaf(fct, wv.z, bb.z), 0.0f);
    r.w = fmaxf(fmaf(fct, wv.w, bb.w), 0.0f);
    ((float4*)x3)[(size_t)n * 8 + lane] = r;
}

// ============ Node kernels: h = x@W stored as packed fp16 rows ================
template <int IN, int HC>
__global__ __launch_bounds__(256) void gat_node_f16_kernel(
    const float* __restrict__ x, const float* __restrict__ W,
    int4* __restrict__ hp, int N)
{
    int n = blockIdx.x * blockDim.x + threadIdx.x;
    if (n >= N) return;
    float xv[IN];
#pragma unroll
    for (int k = 0; k < IN; ++k) xv[k] = x[n * IN + k];
    float hv[HC];
#pragma unroll
    for (int j = 0; j < HC; ++j) {
        float acc = 0.0f;
#pragma unroll
        for (int k = 0; k < IN; ++k) acc = fmaf(xv[k], W[k * HC + j], acc);
        hv[j] = acc;
    }
#pragma unroll
    for (int q = 0; q < HC / 8; ++q)
        hp[(size_t)n * (HC / 8) + q] = f_to_h8(hv + q * 8);
}

// ============ Layer-2 gather: H=4, fp16 rows (32 B), scores on the fly, W=8 ===
__global__ __launch_bounds__(256) void gat_gather2_kernel(
    const int* __restrict__ row_start, const int* __restrict__ degv,
    const int* __restrict__ col, const int4* __restrict__ hp,
    const float* __restrict__ a_src, const float* __restrict__ a_dst,
    const float* __restrict__ bias, float* __restrict__ xout, int N)
{
    int t = blockIdx.x * 256 + threadIdx.x;
    int n = t >> 3, lane = t & 7;
    if (n >= N) return;
    float As[16], Ad[16];
#pragma unroll
    for (int j = 0; j < 16; ++j) { As[j] = a_src[j]; Ad[j] = a_dst[j]; }
    float hn[16];
    h8_to_f(hp[(size_t)n * 2], hn);
    h8_to_f(hp[(size_t)n * 2 + 1], hn + 8);
    float ald[4];
#pragma unroll
    for (int hd = 0; hd < 4; ++hd) {
        float d = 0.0f;
#pragma unroll
        for (int c = 0; c < 4; ++c) d = fmaf(hn[hd * 4 + c], Ad[hd * 4 + c], d);
        ald[hd] = d;
    }
    float num[16], den[4];
    if (lane == 0) {
#pragma unroll
        for (int hd = 0; hd < 4; ++hd) {
            float a = 0.0f;
#pragma unroll
            for (int c = 0; c < 4; ++c) a = fmaf(hn[hd * 4 + c], As[hd * 4 + c], a);
            float w = __expf(lrelu(a + ald[hd]));
            den[hd] = w;
#pragma unroll
            for (int c = 0; c < 4; ++c) num[hd * 4 + c] = w * hn[hd * 4 + c];
        }
    } else {
#pragma unroll
        for (int j = 0; j < 16; ++j) num[j] = 0.0f;
#pragma unroll
        for (int hd = 0; hd < 4; ++hd) den[hd] = 0.0f;
    }
    int start = row_start[n];
    int end = start + degv[n];
    for (int e = start + lane; e < end; e += 8) {
        int s = col[e];
        if (s == n) continue;
        float hs[16];
        h8_to_f(hp[(size_t)s * 2], hs);
        h8_to_f(hp[(size_t)s * 2 + 1], hs + 8);
#pragma unroll
        for (int hd = 0; hd < 4; ++hd) {
            float a = 0.0f;
#pragma unroll
            for (int c = 0; c < 4; ++c) a = fmaf(hs[hd * 4 + c], As[hd * 4 + c], a);
            float w = __expf(lrelu(a + ald[hd]));
            den[hd] += w;
#pragma unroll
            for (int c = 0; c < 4; ++c) num[hd * 4 + c] = fmaf(w, hs[hd * 4 + c], num[hd * 4 + c]);
        }
    }
#pragma unroll
    for (int m = 1; m < 8; m <<= 1) {
#pragma unroll
        for (int hd = 0; hd < 4; ++hd) den[hd] += __shfl_xor(den[hd], m);
#pragma unroll
        for (int j = 0; j < 16; ++j) num[j] += __shfl_xor(num[j], m);
    }
    if (lane < 4) {
        float inv = 1.0f / den[lane];
        const float4 bb = ((const float4*)bias)[lane];
        float4 r;
        r.x = fmaxf(fmaf(num[lane * 4 + 0], inv, bb.x), 0.0f);
        r.y = fmaxf(fmaf(num[lane * 4 + 1], inv, bb.y), 0.0f);
        r.z = fmaxf(fmaf(num[lane * 4 + 2], inv, bb.z), 0.0f);
        r.w = fmaxf(fmaf(num[lane * 4 + 3], inv, bb.w), 0.0f);
        ((float4*)xout)[(size_t)n * 4 + lane] = r;
    }
}

// ============ Layer-3 gather: H=2, fp16 rows (16 B), W=4, fp16 x6 out =========
__global__ __launch_bounds__(256) void gat_gather3_kernel(
    const int* __restrict__ row_start, const int* __restrict__ degv,
    const int* __restrict__ col, const int4* __restrict__ hp,
    const float* __restrict__ a_src, const float* __restrict__ a_dst,
    const float* __restrict__ bias, int4* __restrict__ x6p, int N)
{
    int t = blockIdx.x * 256 + threadIdx.x;
    int n = t >> 2, lane = t & 3;
    if (n >= N) return;
    float As[8], Ad[8];
#pragma unroll
    for (int j = 0; j < 8; ++j) { As[j] = a_src[j]; Ad[j] = a_dst[j]; }
    float hn[8];
    h8_to_f(hp[n], hn);
    float ald[2];
#pragma unroll
    for (int hd = 0; hd < 2; ++hd) {
        float d = 0.0f;
#pragma unroll
        for (int c = 0; c < 4; ++c) d = fmaf(hn[hd * 4 + c], Ad[hd * 4 + c], d);
        ald[hd] = d;
    }
    float num[8], den[2];
    if (lane == 0) {
#pragma unroll
        for (int hd = 0; hd < 2; ++hd) {
            float a = 0.0f;
#pragma unroll
            for (int c = 0; c < 4; ++c) a = fmaf(hn[hd * 4 + c], As[hd * 4 + c], a);
            float w = __expf(lrelu(a + ald[hd]));
            den[hd] = w;
#pragma unroll
            for (int c = 0; c < 4; ++c) num[hd * 4 + c] = w * hn[hd * 4 + c];
        }
    } else {
#pragma unroll
        for (int j = 0; j < 8; ++j) num[j] = 0.0f;
        den[0] = den[1] = 0.0f;
    }
    int start = row_start[n];
    int end = start + degv[n];
    for (int e = start + lane; e < end; e += 4) {
        int s = col[e];
        if (s == n) continue;
        float hs[8];
        h8_to_f(hp[s], hs);
#pragma unroll
        for (int hd = 0; hd < 2; ++hd) {
            float a = 0.0f;
#pragma unroll
            for (int c = 0; c < 4; ++c) a = fmaf(hs[hd * 4 + c], As[hd * 4 + c], a);
            float w = __expf(lrelu(a + ald[hd]));
            den[hd] += w;
#pragma unroll
            for (int c = 0; c < 4; ++c) num[hd * 4 + c] = fmaf(w, hs[hd * 4 + c], num[hd * 4 + c]);
        }
    }
#pragma unroll
    for (int m = 1; m < 4; m <<= 1) {
        den[0] += __shfl_xor(den[0], m);
        den[1] += __shfl_xor(den[1], m);
#pragma unroll
        for (int j = 0; j < 8; ++j) num[j] += __shfl_xor(num[j], m);
    }
    if (lane == 0) {
        float o[8];
        float i0 = 1.0f / den[0], i1 = 1.0f / den[1];
#pragma unroll
        for (int c = 0; c < 4; ++c) {
            o[c]     = fmaxf(fmaf(num[c], i0, bias[c]), 0.0f);
            o[4 + c] = fmaxf(fmaf(num[4 + c], i1, bias[4 + c]), 0.0f);
        }
        x6p[n] = f_to_h8(o);
    }
}

// ============ Final scoring: by-src CSR, fp16 x6, W=4 =========================
// Algebra: local = x6[n] . R3raw[n], so the edge loop only sums neighbors.
__global__ __launch_bounds__(256) void score_gather_kernel(
    const int* __restrict__ row_start, const int* __restrict__ degv,
    const int* __restrict__ col, const int4* __restrict__ x6p,
    const float* __restrict__ lin2_w, float* __restrict__ out, int N)
{
    int t = blockIdx.x * 256 + threadIdx.x;
    int n = t >> 2, lane = t & 3;
    if (n >= N) return;
    float sx[8];
    h8_to_f(x6p[n], sx);
    float r[8];
    int sc = 0;
    if (lane == 0) {
#pragma unroll
        for (int j = 0; j < 8; ++j) r[j] = sx[j];   // self term of R3raw
    } else {
#pragma unroll
        for (int j = 0; j < 8; ++j) r[j] = 0.0f;
    }
    int start = row_start[n];
    int dg = degv[n];
    int end = start + dg;
    for (int e = start + lane; e < end; e += 4) {
        int d = col[e];
        if (d == n) { ++sc; continue; }
        float dx[8];
        h8_to_f(x6p[d], dx);
#pragma unroll
        for (int j = 0; j < 8; ++j) r[j] += dx[j];
    }
#pragma unroll
    for (int m = 1; m < 4; m <<= 1) {
        sc += __shfl_xor(sc, m);
#pragma unroll
        for (int j = 0; j < 8; ++j) r[j] += __shfl_xor(r[j], m);
    }
    if (lane == 0) {
        float invd = 1.0f / (1.0f + (float)(dg - sc));
        float loc = 0.0f, g = 0.0f;
#pragma unroll
        for (int j = 0; j < 8; ++j) {
            loc = fmaf(sx[j], r[j], loc);
            g   = fmaf(r[j], lin2_w[j], g);
        }
        out[n] = (loc + g) * invd;
    }
}

extern "C" void kernel_launch(void* const* d_in, const int* in_sizes, int n_in,
                              void* d_out, int out_size, void* d_ws, size_t ws_size,
                              hipStream_t stream)
{
    const float* x1     = (const float*)d_in[0];
    const int*   ei     = (const int*)d_in[2];
    const float* lin1_w = (const float*)d_in[4];
    const float* lin1_b = (const float*)d_in[5];
    const float* lin2_w = (const float*)d_in[6];
    const float* W1     = (const float*)d_in[7];
    const float* a_src1 = (const float*)d_in[8];
    const float* a_dst1 = (const float*)d_in[9];
    const float* b1     = (const float*)d_in[10];
    const float* W2     = (const float*)d_in[11];
    const float* a_src2 = (const float*)d_in[12];
    const float* a_dst2 = (const float*)d_in[13];
    const float* b2     = (const float*)d_in[14];
    const float* W3     = (const float*)d_in[15];
    const float* a_src3 = (const float*)d_in[16];
    const float* a_dst3 = (const float*)d_in[17];
    const float* b3     = (const float*)d_in[18];
    float* out = (float*)d_out;

    const int N = in_sizes[0] / 7;   // 100000
    const int E = in_sizes[2] / 2;   // 3200000
    const int* src = ei;
    const int* dst = ei + E;

    const int npr = (N + P - 1) / P; // 391 nodes per range (<= 512 for build TB)
    const unsigned int mg = (unsigned int)((0x100000000ULL + npr - 1) / (unsigned long long)npr);
    const int PB = (E + CHSZ - 1) / CHSZ;  // 782 chunks

    // ---- workspace layout ----
    size_t Ns = (size_t)N, Es = (size_t)E;
    int* ideg_dst = (int*)d_ws;
    int* ideg_src = ideg_dst + Ns;
    int* irow_dst = ideg_src + Ns;
    int* irow_src = irow_dst + Ns;
    int* gcount   = irow_src + Ns;        // 2P ints (totals after part2)
    int* iebase   = gcount + 2 * P;       // 2P ints
    int* icol_dst = iebase + 2 * P;
    int* icol_src = icol_dst + Es;
    float* f = (float*)(icol_src + Es);   // 80N float region
    // staging (2*P*CAP = 7.17M words = 71.7N) aliases f; dies after build_kernel
    unsigned int* stgd = (unsigned int*)f;
    unsigned int* stgs = stgd + (size_t)P * CAP;
    // float/fp16 buffers, born after build (disjoint; total 65N <= 80N):
    float* h0  = f;                        // [0, N)
    float* x3  = f + Ns;                   // [N, 33N)      fp32 [N,32]
    int4*  h2p = (int4*)(f + 33 * Ns);     // [33N, 41N)    fp16 [N,16] (32 B rows)
    float* x4  = f + 41 * Ns;              // [41N, 57N)    fp32 [N,16]
    int4*  h3p = (int4*)(f + 57 * Ns);     // [57N, 61N)    fp16 [N,8]  (16 B rows)
    int4*  x6p = (int4*)(f + 61 * Ns);     // [61N, 65N)    fp16 [N,8]

    const int TB = 256;
    const int gN = (N + TB - 1) / TB;
    const int g8 = (8 * N + TB - 1) / TB;
    const int g4 = (4 * N + TB - 1) / TB;

    // ---- CSR build: single-pass partition (per-dir blocks) + per-range sort ----
    hipMemsetAsync(gcount, 0, 2 * P * sizeof(int), stream);
    part2_kernel<<<2 * PB, 256, 0, stream>>>(src, dst, gcount, stgd, stgs, E, npr, mg);
    ebase_kernel<<<1, 2 * P, 0, stream>>>(gcount, iebase);
    build_kernel<<<2 * P, 512, 0, stream>>>(stgd, stgs, gcount, iebase,
                                            icol_dst, icol_src,
                                            ideg_dst, ideg_src,
                                            irow_dst, irow_src, N, npr);

    // ---- Layer 1: rank-1 fast path ----
    l1h0_kernel<<<gN, TB, 0, stream>>>(x1, lin1_w, lin1_b, h0, N);
    gat_gather1_kernel<<<g8, TB, 0, stream>>>(irow_dst, ideg_dst, icol_dst,
                                              h0, W1, a_src1, a_dst1, b1, x3, N);

    // ---- Layer 2: [N,32] -> [N,16], H=4 ----
    gat_node_f16_kernel<32, 16><<<gN, TB, 0, stream>>>(x3, W2, h2p, N);
    gat_gather2_kernel<<<g8, TB, 0, stream>>>(irow_dst, ideg_dst, icol_dst,
                                              h2p, a_src2, a_dst2, b2, x4, N);

    // ---- Layer 3: [N,16] -> [N,8], H=2 ----
    gat_node_f16_kernel<16, 8><<<gN, TB, 0, stream>>>(x4, W3, h3p, N);
    gat_gather3_kernel<<<g4, TB, 0, stream>>>(irow_dst, ideg_dst, icol_dst,
                                              h3p, a_src3, a_dst3, b3, x6p, N);

    // ---- Final scoring (by-src CSR) ----
    score_gather_kernel<<<g4, TB, 0, stream>>>(irow_src, ideg_src, icol_src,
                                               x6p, lin2_w, out, N);
}